// Round 7
// baseline (285.949 us; speedup 1.0000x reference)
//
#include <hip/hip_runtime.h>
#include <hip/hip_bf16.h>

// Problem constants (from reference)
#define GN 50000
#define GF 128
#define GH 4
#define GC 32
#define GE 800000
#define GETOT (GE + GN)   // edges + self loops
#define HC 128            // H*C
#define NEG 0.2f

#define TBLK ((GN + 63) / 64)       // 782 transform blocks (64 rows each, m-loop inside)
#define SBLK ((GETOT + 255) / 256)  // 3321 slot blocks

typedef __bf16 bf16x8 __attribute__((ext_vector_type(8)));
typedef float  f32x4  __attribute__((ext_vector_type(4)));
typedef unsigned short ushort8 __attribute__((ext_vector_type(8)));

__device__ __forceinline__ ushort f32_to_bf16_rne(float f) {
    unsigned u = __float_as_uint(f);
    return (ushort)((u + 0x7fffu + ((u >> 16) & 1u)) >> 16);   // finite data
}

__device__ __forceinline__ bf16x8 cvt8(const float* p) {
    float4 v0 = *(const float4*)p;
    float4 v1 = *(const float4*)(p + 4);
    ushort8 o;
    o[0] = f32_to_bf16_rne(v0.x); o[1] = f32_to_bf16_rne(v0.y);
    o[2] = f32_to_bf16_rne(v0.z); o[3] = f32_to_bf16_rne(v0.w);
    o[4] = f32_to_bf16_rne(v1.x); o[5] = f32_to_bf16_rne(v1.y);
    o[6] = f32_to_bf16_rne(v1.z); o[7] = f32_to_bf16_rne(v1.w);
    return __builtin_bit_cast(bf16x8, o);
}

// DPP in-row (16-lane) reduce helper: v += v[permuted lane]. VALU-pipe only.
template<int CTRL>
__device__ __forceinline__ float dpp_add(float v) {
    int s = __builtin_bit_cast(int, v);
    int y = __builtin_amdgcn_update_dpp(s, s, CTRL, 0xF, 0xF, false);
    return v + __builtin_bit_cast(float, y);
}

// ---------------------------------------------------------------------------
// Kernel 0: cast W to bf16 table Wb[m][col][k]  +  zero deg (replaces memset)
// ---------------------------------------------------------------------------
__global__ __launch_bounds__(256) void conv_w(
    const float* __restrict__ Wl, const float* __restrict__ Wr,
    const float* __restrict__ Ws, ushort* __restrict__ Wb,
    int* __restrict__ deg)
{
    int idx = blockIdx.x * 256 + threadIdx.x;
    if (idx < 3 * GF * GF / 8) {            // 6144 groups of 8
        int m = idx / 2048;
        int e = (idx - m * 2048) * 8;
        const float* W = (m == 0) ? Wl : (m == 1) ? Wr : Ws;
        float4 v0 = *(const float4*)&W[e];
        float4 v1 = *(const float4*)&W[e + 4];
        ushort8 o;
        o[0] = f32_to_bf16_rne(v0.x); o[1] = f32_to_bf16_rne(v0.y);
        o[2] = f32_to_bf16_rne(v0.z); o[3] = f32_to_bf16_rne(v0.w);
        o[4] = f32_to_bf16_rne(v1.x); o[5] = f32_to_bf16_rne(v1.y);
        o[6] = f32_to_bf16_rne(v1.z); o[7] = f32_to_bf16_rne(v1.w);
        *(ushort8*)&Wb[m * 16384 + e] = o;
    }
    int z = idx - 6144;                     // 12500 int4 = 50000 ints exactly
    if (z >= 0 && z < GN / 4)
        *(int4*)&deg[z * 4] = make_int4(0, 0, 0, 0);
}

// ---------------------------------------------------------------------------
// Kernel 1 (fused): grid = SBLK + TBLK.
//  blocks [0, SBLK): slot pass — deg histogram + per-edge slot (atomic)
//  blocks [SBLK,..): MFMA transforms, m-loop INSIDE: x read once, A-frags
//    persist in registers across all three W matrices (96 MFMA per wave).
// Neither path uses LDS or barriers -> safe grid partition.
// mfma_f32_16x16x32_bf16: A row=lane&15, k=(lane>>4)*8+j; B col=lane&15;
// D col=lane&15, row=(lane>>4)*4+reg  [m89-verified].
// m=0 (xl) / m=2 (xs) write interleaved bf16 table xi[row][4-ushort groups]
// = {xl[2l],xl[2l+1],xs[2l],xs[2l+1]}; m=1 writes xr f32.
// ---------------------------------------------------------------------------
__global__ __launch_bounds__(256) void fused_transform_slot(
    const float* __restrict__ x, const ushort* __restrict__ Wb,
    const float* __restrict__ bl, const float* __restrict__ br,
    const float* __restrict__ bs,
    const int* __restrict__ ei, int* __restrict__ deg, int* __restrict__ slot,
    ushort* __restrict__ xi, float* __restrict__ xr)
{
    if (blockIdx.x < SBLK) {
        int e = blockIdx.x * 256 + threadIdx.x;
        if (e < GETOT) {
            int dst = (e < GE) ? ei[GE + e] : (e - GE);
            slot[e] = atomicAdd(&deg[dst], 1);
        }
        return;
    }

    const int bx    = blockIdx.x - SBLK;
    const int wave  = threadIdx.x >> 6;
    const int lane  = threadIdx.x & 63;
    const int colb  = lane & 15;
    const int klane = lane >> 4;
    const int row0  = bx * 64 + wave * 16;

    // A-frags: 4 k-blocks, loaded f32 once and converted in-register; persist.
    bf16x8 a[4];
    {
        int rA = row0 + colb;
        const float* ap = x + (size_t)min(rA, GN - 1) * GF + klane * 8;
#pragma unroll
        for (int kb = 0; kb < 4; ++kb)
            a[kb] = cvt8(ap + kb * 32);
    }

    for (int m = 0; m < 3; ++m) {
        const ushort* wb = Wb + m * 16384 + colb * GF + klane * 8;

        f32x4 acc[8];
#pragma unroll
        for (int n = 0; n < 8; ++n) acc[n] = (f32x4){0.f, 0.f, 0.f, 0.f};

#pragma unroll
        for (int kb = 0; kb < 4; ++kb) {
            bf16x8 b[8];
#pragma unroll
            for (int n = 0; n < 8; ++n)
                b[n] = *(const bf16x8*)(wb + n * 2048 + kb * 32);
#pragma unroll
            for (int n = 0; n < 8; ++n)
                acc[n] = __builtin_amdgcn_mfma_f32_16x16x32_bf16(a[kb], b[n], acc[n], 0, 0, 0);
        }

        const float* bia = (m == 0) ? bl : (m == 1) ? br : bs;
        const int moff = (m == 2) ? 2 : 0;
        const int rD0 = row0 + klane * 4;
#pragma unroll
        for (int n = 0; n < 8; ++n) {
            int col = n * 16 + colb;
            float bv = bia[col];
#pragma unroll
            for (int r = 0; r < 4; ++r) {
                int row = rD0 + r;
                if (row < GN) {
                    float v = acc[n][r] + bv;
                    if (m == 1)
                        xr[(size_t)row * HC + col] = v;
                    else
                        xi[(size_t)row * 256 + (col >> 1) * 4 + (col & 1) + moff]
                            = f32_to_bf16_rne(v);
                }
            }
        }
    }
}

// ---------------------------------------------------------------------------
// Kernel 2: exclusive prefix sum deg -> rowstart[N+1]. 1 block x 1024, int4.
// ---------------------------------------------------------------------------
__global__ __launch_bounds__(1024) void scan_kernel(const int* __restrict__ deg,
                                                    int* __restrict__ rowstart)
{
    __shared__ int sums[1024];
    const int t = threadIdx.x;
    const int CH = 52;                  // 13 int4; 1024*52 = 53248 >= 50000
    const int start = t * CH;
    const int end = min(start + CH, GN);

    int s = 0;
    if (start + CH <= GN) {
#pragma unroll
        for (int g = 0; g < 13; ++g) {
            int4 v = *(const int4*)&deg[start + g * 4];
            s += v.x + v.y + v.z + v.w;
        }
    } else {
        for (int i = start; i < end; ++i) s += deg[i];
    }
    sums[t] = s;
    __syncthreads();
    for (int off = 1; off < 1024; off <<= 1) {
        int v = (t >= off) ? sums[t - off] : 0;
        __syncthreads();
        sums[t] += v;
        __syncthreads();
    }
    int run = sums[t] - s;   // exclusive prefix of this thread's chunk
    if (start + CH <= GN) {
#pragma unroll
        for (int g = 0; g < 13; ++g) {
            int4 v = *(const int4*)&deg[start + g * 4];
            int4 w;
            w.x = run;
            w.y = run + v.x;
            w.z = run + v.x + v.y;
            w.w = run + v.x + v.y + v.z;
            run += v.x + v.y + v.z + v.w;
            *(int4*)&rowstart[start + g * 4] = w;
        }
    } else {
        for (int i = start; i < end; ++i) { rowstart[i] = run; run += deg[i]; }
    }
    if (t == 1023) rowstart[GN] = run;   // run == total (empty tail chunk)
}

// ---------------------------------------------------------------------------
// Kernel 3: atomic-free scatter into CSR-by-dst
// ---------------------------------------------------------------------------
__global__ void scatter_kernel(const int* __restrict__ ei,
                               const int* __restrict__ rowstart,
                               const int* __restrict__ slot,
                               int* __restrict__ csr_src)
{
    int e = blockIdx.x * 256 + threadIdx.x;
    if (e >= GETOT) return;
    int src, dst;
    if (e < GE) { src = ei[e]; dst = ei[GE + e]; }
    else        { src = dst = e - GE; }
    csr_src[rowstart[dst] + slot[e]] = src;
}

// ---------------------------------------------------------------------------
// Kernel 4: fused per-node GATv2, single pass, 4x-unrolled, DPP reduce:
//   out = (sum_e exp(score_e) * xs[src_e]) / (sum_e exp(score_e)) + bias
// One wave per node; lane l owns channels {2l,2l+1}, head = l>>4 (= DPP row).
// Head-group sum: quad_perm xor1, xor2, then row_ror:4 + row_ror:8 rotation
// reduce (exact within 16 lanes) — all VALU-pipe, no ds_bpermute.
// Tail edges masked via pe=0 (their src defaults to 0 -> safe gather of xi[0]).
// No max-subtraction: scores ~N(0,<1), f32 exp safe, ratio exact.
// ---------------------------------------------------------------------------
__device__ __forceinline__ void edge_acc(uint2 xv, float2 xr2, float2 at2,
                                         bool live, float& denom,
                                         float& ax, float& ay)
{
    float zx = __uint_as_float((xv.x & 0xffffu) << 16) + xr2.x;
    float zy = __uint_as_float(xv.x & 0xffff0000u) + xr2.y;
    zx = (zx > 0.f) ? zx : NEG * zx;
    zy = (zy > 0.f) ? zy : NEG * zy;
    float sc = fmaf(zx, at2.x, zy * at2.y);
    sc = dpp_add<0xB1>(sc);    // quad_perm [1,0,3,2]  : + lane^1
    sc = dpp_add<0x4E>(sc);    // quad_perm [2,3,0,1]  : + lane^2
    sc = dpp_add<0x124>(sc);   // row_ror:4            : + rotated quad-sums
    sc = dpp_add<0x128>(sc);   // row_ror:8            : full 16-lane sum
    float pe = live ? __expf(sc) : 0.f;
    denom += pe;
    ax = fmaf(pe, __uint_as_float((xv.y & 0xffffu) << 16), ax);
    ay = fmaf(pe, __uint_as_float(xv.y & 0xffff0000u), ay);
}

__global__ __launch_bounds__(256) void gat_kernel(
    const ushort* __restrict__ xi, const float* __restrict__ xr,
    const float* __restrict__ att, const float* __restrict__ bias,
    const int* __restrict__ rowstart, const int* __restrict__ csr_src,
    float* __restrict__ out)
{
    const int wave = threadIdx.x >> 6;
    const int lane = threadIdx.x & 63;
    const int node = blockIdx.x * 4 + wave;   // grid = N/4 exactly
    const int l4 = lane * 4;                  // ushort offset of this lane's quad

    const float2 xr2 = *(const float2*)&xr[(size_t)node * HC + lane * 2];
    const float2 at2 = *(const float2*)&att[lane * 2];
    const float2 bi2 = *(const float2*)&bias[lane * 2];

    const int s0 = rowstart[node];
    const int s1 = rowstart[node + 1];

    float denom = 0.f, ax = 0.f, ay = 0.f;
    for (int base = s0; base < s1; base += 64) {
        int nsrc = (base + lane < s1) ? csr_src[base + lane] : 0;
        int cnt = min(64, s1 - base);
        for (int t = 0; t < cnt; t += 4) {
            int sA = __shfl(nsrc, t, 64);
            int sB = __shfl(nsrc, t + 1, 64);
            int sC = __shfl(nsrc, t + 2, 64);
            int sD = __shfl(nsrc, t + 3, 64);
            uint2 vA = *(const uint2*)&xi[(size_t)sA * 256 + l4];
            uint2 vB = *(const uint2*)&xi[(size_t)sB * 256 + l4];
            uint2 vC = *(const uint2*)&xi[(size_t)sC * 256 + l4];
            uint2 vD = *(const uint2*)&xi[(size_t)sD * 256 + l4];
            edge_acc(vA, xr2, at2, true,          denom, ax, ay);
            edge_acc(vB, xr2, at2, (t + 1 < cnt), denom, ax, ay);
            edge_acc(vC, xr2, at2, (t + 2 < cnt), denom, ax, ay);
            edge_acc(vD, xr2, at2, (t + 3 < cnt), denom, ax, ay);
        }
    }
    const float inv = 1.f / denom;
    float2 o;
    o.x = fmaf(ax, inv, bi2.x);
    o.y = fmaf(ay, inv, bi2.y);
    *(float2*)&out[(size_t)node * HC + lane * 2] = o;
}

// ---------------------------------------------------------------------------
extern "C" void kernel_launch(void* const* d_in, const int* in_sizes, int n_in,
                              void* d_out, int out_size, void* d_ws, size_t ws_size,
                              hipStream_t stream)
{
    const float* x   = (const float*)d_in[0];
    const int*   ei  = (const int*)  d_in[1];
    const float* Wl  = (const float*)d_in[2];
    const float* bl  = (const float*)d_in[3];
    const float* Wr  = (const float*)d_in[4];
    const float* br  = (const float*)d_in[5];
    const float* Ws  = (const float*)d_in[6];
    const float* bs  = (const float*)d_in[7];
    const float* att = (const float*)d_in[8];
    const float* bias= (const float*)d_in[9];
    float* out = (float*)d_out;

    // ws layout (16B-aligned):
    ushort* xi = (ushort*)d_ws;                     // N*256 bf16   (25.6 MB)
    ushort* Wb = xi + (size_t)GN * 256;             // 3*128*128 bf16 (96 KB)
    float*  xr = (float*)(Wb + 3 * GF * GF);        // N*128 f32    (25.6 MB)
    int* deg      = (int*)(xr + (size_t)GN * HC);   // 200 KB
    int* rowstart = deg + GN;                        // 200 KB
    int* slot     = rowstart + GN + 1;               // 3.4 MB
    int* csr_src  = slot + GETOT;                    // 3.4 MB

    conv_w<<<(6144 + GN / 4 + 255) / 256, 256, 0, stream>>>(Wl, Wr, Ws, Wb, deg);

    fused_transform_slot<<<SBLK + TBLK, 256, 0, stream>>>(
        x, Wb, bl, br, bs, ei, deg, slot, xi, xr);

    scan_kernel<<<1, 1024, 0, stream>>>(deg, rowstart);

    scatter_kernel<<<SBLK, 256, 0, stream>>>(ei, rowstart, slot, csr_src);

    gat_kernel<<<GN / 4, 256, 0, stream>>>((const ushort*)xi, xr, att, bias,
                                           rowstart, csr_src, out);
}

// Round 10
// 248.713 us; speedup vs baseline: 1.1497x; 1.1497x over previous
//
#include <hip/hip_runtime.h>
#include <hip/hip_bf16.h>

// Problem constants (from reference)
#define GN 50000
#define GF 128
#define GH 4
#define GC 32
#define GE 800000
#define GETOT (GE + GN)   // edges + self loops
#define HC 128            // H*C
#define NEG 0.2f

#define TBLK ((GN + 63) / 64)       // 782 transform blocks (64 rows, m-loop inside)
#define SBLK ((GETOT + 255) / 256)  // 3321 slot blocks
#define LDSW 132                    // LDS row stride in words (pad: 2-way banks, 16B-aligned)

typedef __bf16 bf16x8 __attribute__((ext_vector_type(8)));
typedef float  f32x4  __attribute__((ext_vector_type(4)));
typedef unsigned short ushort8 __attribute__((ext_vector_type(8)));

__device__ __forceinline__ uint f32_to_bf16_rne(float f) {
    unsigned u = __float_as_uint(f);
    return (u + 0x7fffu + ((u >> 16) & 1u)) >> 16;   // finite data
}

__device__ __forceinline__ bf16x8 cvt8(const float* p) {
    float4 v0 = *(const float4*)p;
    float4 v1 = *(const float4*)(p + 4);
    ushort8 o;
    o[0] = (ushort)f32_to_bf16_rne(v0.x); o[1] = (ushort)f32_to_bf16_rne(v0.y);
    o[2] = (ushort)f32_to_bf16_rne(v0.z); o[3] = (ushort)f32_to_bf16_rne(v0.w);
    o[4] = (ushort)f32_to_bf16_rne(v1.x); o[5] = (ushort)f32_to_bf16_rne(v1.y);
    o[6] = (ushort)f32_to_bf16_rne(v1.z); o[7] = (ushort)f32_to_bf16_rne(v1.w);
    return __builtin_bit_cast(bf16x8, o);
}

// DPP in-row (16-lane) reduce helper: v += v[permuted lane]. VALU-pipe only.
template<int CTRL>
__device__ __forceinline__ float dpp_add(float v) {
    int s = __builtin_bit_cast(int, v);
    int y = __builtin_amdgcn_update_dpp(s, s, CTRL, 0xF, 0xF, false);
    return v + __builtin_bit_cast(float, y);
}

// ---------------------------------------------------------------------------
// Kernel 0: cast W to bf16 table Wb[m][col][k]  +  zero deg (replaces memset)
// ---------------------------------------------------------------------------
__global__ __launch_bounds__(256) void conv_w(
    const float* __restrict__ Wl, const float* __restrict__ Wr,
    const float* __restrict__ Ws, ushort* __restrict__ Wb,
    int* __restrict__ deg)
{
    int idx = blockIdx.x * 256 + threadIdx.x;
    if (idx < 3 * GF * GF / 8) {            // 6144 groups of 8
        int m = idx / 2048;
        int e = (idx - m * 2048) * 8;
        const float* W = (m == 0) ? Wl : (m == 1) ? Wr : Ws;
        float4 v0 = *(const float4*)&W[e];
        float4 v1 = *(const float4*)&W[e + 4];
        ushort8 o;
        o[0] = (ushort)f32_to_bf16_rne(v0.x); o[1] = (ushort)f32_to_bf16_rne(v0.y);
        o[2] = (ushort)f32_to_bf16_rne(v0.z); o[3] = (ushort)f32_to_bf16_rne(v0.w);
        o[4] = (ushort)f32_to_bf16_rne(v1.x); o[5] = (ushort)f32_to_bf16_rne(v1.y);
        o[6] = (ushort)f32_to_bf16_rne(v1.z); o[7] = (ushort)f32_to_bf16_rne(v1.w);
        *(ushort8*)&Wb[m * 16384 + e] = o;
    }
    int z = idx - 6144;                     // 12500 int4 = 50000 ints exactly
    if (z >= 0 && z < GN / 4)
        *(int4*)&deg[z * 4] = make_int4(0, 0, 0, 0);
}

// ---------------------------------------------------------------------------
// Kernel 1 (fused): grid = TBLK + SBLK (transform FIRST — long-pole blocks).
//  blocks [0, TBLK): MFMA transforms, m-loop inside (x read once); outputs
//    staged in LDS and stored coalesced (uint4/float4) — kills the 2-byte
//    scattered-store write amplification seen in R7 (WRITE 99 MB vs 57 logical).
//  blocks [TBLK,..): slot pass — deg histogram + per-edge slot (atomic).
// xi group layout: group g = {xl[2g], xs[2g], xl[2g+1], xs[2g+1]}
//  -> one lane packs bf16(xl)|bf16(xs)<<16 as a single b32 LDS write.
// mfma_f32_16x16x32_bf16: A row=lane&15, k=(lane>>4)*8+j; B col=lane&15;
// D col=lane&15, row=(lane>>4)*4+reg  [m89-verified].
// ---------------------------------------------------------------------------
__global__ __launch_bounds__(256) void fused_transform_slot(
    const float* __restrict__ x, const ushort* __restrict__ Wb,
    const float* __restrict__ bl, const float* __restrict__ br,
    const float* __restrict__ bs,
    const int* __restrict__ ei, int* __restrict__ deg, int* __restrict__ slot,
    uint* __restrict__ xi, float* __restrict__ xr)
{
    __shared__ float lds_f[64 * LDSW];      // 33 KB, reused (u32 then f32)

    if (blockIdx.x >= TBLK) {
        int e = (blockIdx.x - TBLK) * 256 + threadIdx.x;
        if (e < GETOT) {
            int dst = (e < GE) ? ei[GE + e] : (e - GE);
            slot[e] = atomicAdd(&deg[dst], 1);
        }
        return;
    }

    const int bx    = blockIdx.x;
    const int tid   = threadIdx.x;
    const int wave  = tid >> 6;
    const int lane  = tid & 63;
    const int colb  = lane & 15;
    const int klane = lane >> 4;
    const int row0  = bx * 64 + wave * 16;

    // A-frags: 4 k-blocks, loaded f32 once, converted in-register; persist.
    bf16x8 a[4];
    {
        int rA = row0 + colb;
        const float* ap = x + (size_t)min(rA, GN - 1) * GF + klane * 8;
#pragma unroll
        for (int kb = 0; kb < 4; ++kb)
            a[kb] = cvt8(ap + kb * 32);
    }

    const int woff = colb * GF + klane * 8;
    uint* lds_u = (uint*)lds_f;

    // ---- m=0 (xl) and m=2 (xs): both accs live, packed staging ----
    f32x4 acc0[8], acc2[8];
#pragma unroll
    for (int n = 0; n < 8; ++n) {
        acc0[n] = (f32x4){0.f, 0.f, 0.f, 0.f};
        acc2[n] = (f32x4){0.f, 0.f, 0.f, 0.f};
    }
#pragma unroll
    for (int kb = 0; kb < 4; ++kb) {
        const ushort* w0 = Wb + woff + kb * 32;
        const ushort* w2 = Wb + 2 * 16384 + woff + kb * 32;
#pragma unroll
        for (int n = 0; n < 8; ++n) {
            bf16x8 b0 = *(const bf16x8*)(w0 + n * 2048);
            bf16x8 b2 = *(const bf16x8*)(w2 + n * 2048);
            acc0[n] = __builtin_amdgcn_mfma_f32_16x16x32_bf16(a[kb], b0, acc0[n], 0, 0, 0);
            acc2[n] = __builtin_amdgcn_mfma_f32_16x16x32_bf16(a[kb], b2, acc2[n], 0, 0, 0);
        }
    }
#pragma unroll
    for (int n = 0; n < 8; ++n) {
        int col = n * 16 + colb;
        float blv = bl[col], bsv = bs[col];
#pragma unroll
        for (int r = 0; r < 4; ++r) {
            int rl = wave * 16 + klane * 4 + r;
            uint w = f32_to_bf16_rne(acc0[n][r] + blv)
                   | (f32_to_bf16_rne(acc2[n][r] + bsv) << 16);
            lds_u[rl * LDSW + col] = w;
        }
    }
    __syncthreads();
    // coalesced xi store: 64 rows x 128 words, uint4 chunks
#pragma unroll
    for (int i = 0; i < 8; ++i) {
        int c = i * 256 + tid;            // chunk id: row = c>>5, cin = c&31
        int row = c >> 5, cin = c & 31;
        if (bx * 64 + row < GN) {
            uint4 v = *(uint4*)&lds_u[row * LDSW + cin * 4];
            *(uint4*)&xi[((size_t)(bx * 64 + row)) * 128 + cin * 4] = v;
        }
    }
    __syncthreads();

    // ---- m=1 (xr, f32) ----
    f32x4 acc1[8];
#pragma unroll
    for (int n = 0; n < 8; ++n) acc1[n] = (f32x4){0.f, 0.f, 0.f, 0.f};
#pragma unroll
    for (int kb = 0; kb < 4; ++kb) {
        const ushort* w1 = Wb + 16384 + woff + kb * 32;
#pragma unroll
        for (int n = 0; n < 8; ++n) {
            bf16x8 b1 = *(const bf16x8*)(w1 + n * 2048);
            acc1[n] = __builtin_amdgcn_mfma_f32_16x16x32_bf16(a[kb], b1, acc1[n], 0, 0, 0);
        }
    }
#pragma unroll
    for (int n = 0; n < 8; ++n) {
        int col = n * 16 + colb;
        float bv = br[col];
#pragma unroll
        for (int r = 0; r < 4; ++r) {
            int rl = wave * 16 + klane * 4 + r;
            lds_f[rl * LDSW + col] = acc1[n][r] + bv;
        }
    }
    __syncthreads();
#pragma unroll
    for (int i = 0; i < 8; ++i) {
        int c = i * 256 + tid;
        int row = c >> 5, cin = c & 31;
        if (bx * 64 + row < GN) {
            float4 v = *(float4*)&lds_f[row * LDSW + cin * 4];
            *(float4*)&xr[((size_t)(bx * 64 + row)) * 128 + cin * 4] = v;
        }
    }
}

// ---------------------------------------------------------------------------
// Kernel 2: exclusive prefix sum deg -> rowstart[N+1]. 1 block x 1024, int4.
// ---------------------------------------------------------------------------
__global__ __launch_bounds__(1024) void scan_kernel(const int* __restrict__ deg,
                                                    int* __restrict__ rowstart)
{
    __shared__ int sums[1024];
    const int t = threadIdx.x;
    const int CH = 52;                  // 13 int4; 1024*52 = 53248 >= 50000
    const int start = t * CH;
    const int end = min(start + CH, GN);

    int s = 0;
    if (start + CH <= GN) {
#pragma unroll
        for (int g = 0; g < 13; ++g) {
            int4 v = *(const int4*)&deg[start + g * 4];
            s += v.x + v.y + v.z + v.w;
        }
    } else {
        for (int i = start; i < end; ++i) s += deg[i];
    }
    sums[t] = s;
    __syncthreads();
    for (int off = 1; off < 1024; off <<= 1) {
        int v = (t >= off) ? sums[t - off] : 0;
        __syncthreads();
        sums[t] += v;
        __syncthreads();
    }
    int run = sums[t] - s;   // exclusive prefix of this thread's chunk
    if (start + CH <= GN) {
#pragma unroll
        for (int g = 0; g < 13; ++g) {
            int4 v = *(const int4*)&deg[start + g * 4];
            int4 w;
            w.x = run;
            w.y = run + v.x;
            w.z = run + v.x + v.y;
            w.w = run + v.x + v.y + v.z;
            run += v.x + v.y + v.z + v.w;
            *(int4*)&rowstart[start + g * 4] = w;
        }
    } else {
        for (int i = start; i < end; ++i) { rowstart[i] = run; run += deg[i]; }
    }
    if (t == 1023) rowstart[GN] = run;   // run == total (empty tail chunk)
}

// ---------------------------------------------------------------------------
// Kernel 3: atomic-free scatter into CSR-by-dst
// ---------------------------------------------------------------------------
__global__ void scatter_kernel(const int* __restrict__ ei,
                               const int* __restrict__ rowstart,
                               const int* __restrict__ slot,
                               int* __restrict__ csr_src)
{
    int e = blockIdx.x * 256 + threadIdx.x;
    if (e >= GETOT) return;
    int src, dst;
    if (e < GE) { src = ei[e]; dst = ei[GE + e]; }
    else        { src = dst = e - GE; }
    csr_src[rowstart[dst] + slot[e]] = src;
}

// ---------------------------------------------------------------------------
// Kernel 4: fused per-node GATv2, single pass, 4x-unrolled, DPP reduce:
//   out = (sum_e exp(score_e) * xs[src_e]) / (sum_e exp(score_e)) + bias
// One wave per node; lane l owns channels {2l,2l+1}, head = l>>4 (= DPP row).
// xi group layout: uint2 = {xl[2l]|xs[2l]<<16, xl[2l+1]|xs[2l+1]<<16}.
// Tail edges masked via pe=0 (src defaults to 0 -> safe gather of xi row 0).
// No max-subtraction: scores ~N(0,<1), f32 exp safe, ratio exact.
// ---------------------------------------------------------------------------
__device__ __forceinline__ void edge_acc(uint2 xv, float2 xr2, float2 at2,
                                         bool live, float& denom,
                                         float& ax, float& ay)
{
    float zx = __uint_as_float((xv.x & 0xffffu) << 16) + xr2.x;   // xl[2l]
    float zy = __uint_as_float((xv.y & 0xffffu) << 16) + xr2.y;   // xl[2l+1]
    zx = (zx > 0.f) ? zx : NEG * zx;
    zy = (zy > 0.f) ? zy : NEG * zy;
    float sc = fmaf(zx, at2.x, zy * at2.y);
    sc = dpp_add<0xB1>(sc);    // quad_perm [1,0,3,2]  : + lane^1
    sc = dpp_add<0x4E>(sc);    // quad_perm [2,3,0,1]  : + lane^2
    sc = dpp_add<0x124>(sc);   // row_ror:4
    sc = dpp_add<0x128>(sc);   // row_ror:8 -> full 16-lane sum
    float pe = live ? __expf(sc) : 0.f;
    denom += pe;
    ax = fmaf(pe, __uint_as_float(xv.x & 0xffff0000u), ax);       // xs[2l]
    ay = fmaf(pe, __uint_as_float(xv.y & 0xffff0000u), ay);       // xs[2l+1]
}

__global__ __launch_bounds__(256) void gat_kernel(
    const uint* __restrict__ xi, const float* __restrict__ xr,
    const float* __restrict__ att, const float* __restrict__ bias,
    const int* __restrict__ rowstart, const int* __restrict__ csr_src,
    float* __restrict__ out)
{
    const int wave = threadIdx.x >> 6;
    const int lane = threadIdx.x & 63;
    const int node = blockIdx.x * 4 + wave;   // grid = N/4 exactly
    const int l2 = lane * 2;                  // uint offset of this lane's pair

    const float2 xr2 = *(const float2*)&xr[(size_t)node * HC + l2];
    const float2 at2 = *(const float2*)&att[l2];
    const float2 bi2 = *(const float2*)&bias[l2];

    const int s0 = rowstart[node];
    const int s1 = rowstart[node + 1];

    float denom = 0.f, ax = 0.f, ay = 0.f;
    for (int base = s0; base < s1; base += 64) {
        int nsrc = (base + lane < s1) ? csr_src[base + lane] : 0;
        int cnt = min(64, s1 - base);
        for (int t = 0; t < cnt; t += 4) {
            int sA = __shfl(nsrc, t, 64);
            int sB = __shfl(nsrc, t + 1, 64);
            int sC = __shfl(nsrc, t + 2, 64);
            int sD = __shfl(nsrc, t + 3, 64);
            uint2 vA = *(const uint2*)&xi[(size_t)sA * 128 + l2];
            uint2 vB = *(const uint2*)&xi[(size_t)sB * 128 + l2];
            uint2 vC = *(const uint2*)&xi[(size_t)sC * 128 + l2];
            uint2 vD = *(const uint2*)&xi[(size_t)sD * 128 + l2];
            edge_acc(vA, xr2, at2, true,          denom, ax, ay);
            edge_acc(vB, xr2, at2, (t + 1 < cnt), denom, ax, ay);
            edge_acc(vC, xr2, at2, (t + 2 < cnt), denom, ax, ay);
            edge_acc(vD, xr2, at2, (t + 3 < cnt), denom, ax, ay);
        }
    }
    const float inv = 1.f / denom;
    float2 o;
    o.x = fmaf(ax, inv, bi2.x);
    o.y = fmaf(ay, inv, bi2.y);
    *(float2*)&out[(size_t)node * HC + l2] = o;
}

// ---------------------------------------------------------------------------
extern "C" void kernel_launch(void* const* d_in, const int* in_sizes, int n_in,
                              void* d_out, int out_size, void* d_ws, size_t ws_size,
                              hipStream_t stream)
{
    const float* x   = (const float*)d_in[0];
    const int*   ei  = (const int*)  d_in[1];
    const float* Wl  = (const float*)d_in[2];
    const float* bl  = (const float*)d_in[3];
    const float* Wr  = (const float*)d_in[4];
    const float* br  = (const float*)d_in[5];
    const float* Ws  = (const float*)d_in[6];
    const float* bs  = (const float*)d_in[7];
    const float* att = (const float*)d_in[8];
    const float* bias= (const float*)d_in[9];
    float* out = (float*)d_out;

    // ws layout (16B-aligned):
    uint*   xi = (uint*)d_ws;                       // N*128 u32 (25.6 MB)
    ushort* Wb = (ushort*)(xi + (size_t)GN * 128);  // 3*128*128 bf16 (96 KB)
    float*  xr = (float*)(Wb + 3 * GF * GF);        // N*128 f32 (25.6 MB)
    int* deg      = (int*)(xr + (size_t)GN * HC);   // 200 KB
    int* rowstart = deg + GN;                        // 200 KB
    int* slot     = rowstart + GN + 1;               // 3.4 MB
    int* csr_src  = slot + GETOT;                    // 3.4 MB

    conv_w<<<(6144 + GN / 4 + 255) / 256, 256, 0, stream>>>(Wl, Wr, Ws, Wb, deg);

    fused_transform_slot<<<TBLK + SBLK, 256, 0, stream>>>(
        x, Wb, bl, br, bs, ei, deg, slot, xi, xr);

    scan_kernel<<<1, 1024, 0, stream>>>(deg, rowstart);

    scatter_kernel<<<SBLK, 256, 0, stream>>>(ei, rowstart, slot, csr_src);

    gat_kernel<<<GN / 4, 256, 0, stream>>>((const uint*)xi, xr, att, bias,
                                           rowstart, csr_src, out);
}